// Round 3
// baseline (1096.596 us; speedup 1.0000x reference)
//
#include <hip/hip_runtime.h>

// Masked mean-pool: out[b,d] = sum_s embed[b,s,d]*mask[b,s] / sum_s mask[b,s]
// mask[b,s] = token_ids[b,s] not in {0 (PAD), 101 (CLS), 102 (SEP)}
//
// B=512, S=512, D=768, fp32. Streaming-read bound: ~805 MB embed.
// Roofline @6.3 TB/s achievable: ~128 us.
//
// V4 = DIAGNOSTIC ROUND. V1/V2/V3 (three structurally different kernels,
// 1.5-8 waves/SIMD, strided vs contiguous) all measured 991-999 us -> dur_us
// is kernel-structure-independent. Top-5 dispatches are all ~505us 3.2GB
// harness poison fills; our kernel never appears (so it is <500us). To
// separate "kernel genuinely capped at ~1.64 TB/s" from "harness-fixed
// overhead", this version streams embed TWICE (npass=2, runtime arg so the
// compiler can't dedup). Mean is scale-invariant (2*sum / 2*cnt) -> output
// unchanged. dur_us delta tells us the kernel's true marginal cost per pass,
// and if the kernel is >512us it enters top-5 with full counters.

constexpr int B  = 512;
constexpr int S  = 512;
constexpr int D  = 768;
constexpr int NV = D / 4;      // 192 float4 columns per row
constexpr int P  = 4;          // s-parts per batch row
constexpr int SP = S / P;      // 128 rows per part
constexpr int WAVES = 4;       // 256 threads per block
constexpr int RW = SP / WAVES; // 32 consecutive rows per wave

__global__ __launch_bounds__(256) void partial_kernel(
    const float4* __restrict__ embed,   // [B, S, NV]
    const int*    __restrict__ tok,     // [B, S]
    float4*       __restrict__ ws_sum,  // [B*P, NV]
    float*        __restrict__ ws_cnt,  // [B*P]
    int npass)
{
    const int bp   = blockIdx.x;        // b*P + p
    const int b    = bp >> 2;
    const int p    = bp & (P - 1);
    const int t    = threadIdx.x;
    const int w    = t >> 6;
    const int lane = t & 63;

    __shared__ float  maskf[SP];            // 512 B
    __shared__ float4 sacc[WAVES][NV];      // 12 KB
    __shared__ float  scnt[WAVES];

    const int sbase = p * SP;

    // Stage mask for this s-part (coalesced, threads 0..127).
    if (t < SP) {
        const int id = tok[b * S + sbase + t];
        maskf[t] = (id != 0 && id != 101 && id != 102) ? 1.0f : 0.0f;
    }
    __syncthreads();

    // Wave w streams rows [r0, r0+RW): contiguous 96 KB per pass.
    const int r0 = w * RW;
    const float4* rowp = embed + ((size_t)b * S + sbase + r0) * NV + lane;

    float4 a0 = make_float4(0.f, 0.f, 0.f, 0.f);
    float4 a1 = make_float4(0.f, 0.f, 0.f, 0.f);
    float4 a2 = make_float4(0.f, 0.f, 0.f, 0.f);
    float  cnt = 0.f;

    for (int ps = 0; ps < npass; ++ps) {
#pragma unroll 2
        for (int r = 0; r < RW; ++r) {
            const float  m  = maskf[r0 + r];      // same-address LDS broadcast
            const float4 v0 = rowp[(size_t)r * NV];
            const float4 v1 = rowp[(size_t)r * NV + 64];
            const float4 v2 = rowp[(size_t)r * NV + 128];
            cnt += m;
            a0.x = fmaf(v0.x, m, a0.x); a0.y = fmaf(v0.y, m, a0.y);
            a0.z = fmaf(v0.z, m, a0.z); a0.w = fmaf(v0.w, m, a0.w);
            a1.x = fmaf(v1.x, m, a1.x); a1.y = fmaf(v1.y, m, a1.y);
            a1.z = fmaf(v1.z, m, a1.z); a1.w = fmaf(v1.w, m, a1.w);
            a2.x = fmaf(v2.x, m, a2.x); a2.y = fmaf(v2.y, m, a2.y);
            a2.z = fmaf(v2.z, m, a2.z); a2.w = fmaf(v2.w, m, a2.w);
        }
    }

    sacc[w][lane]       = a0;
    sacc[w][lane + 64]  = a1;
    sacc[w][lane + 128] = a2;
    if (lane == 0) scnt[w] = cnt;
    __syncthreads();

    // Reduce 4 waves -> one partial per (b,p). Threads 0..191.
    if (t < NV) {
        float4 s0 = sacc[0][t];
        const float4 s1 = sacc[1][t];
        const float4 s2 = sacc[2][t];
        const float4 s3 = sacc[3][t];
        s0.x += s1.x + s2.x + s3.x;
        s0.y += s1.y + s2.y + s3.y;
        s0.z += s1.z + s2.z + s3.z;
        s0.w += s1.w + s2.w + s3.w;
        ws_sum[(size_t)bp * NV + t] = s0;
    }
    if (t == 0) ws_cnt[bp] = scnt[0] + scnt[1] + scnt[2] + scnt[3];
}

__global__ __launch_bounds__(NV) void finalize_kernel(
    const float4* __restrict__ ws_sum,  // [B*P, NV]
    const float*  __restrict__ ws_cnt,  // [B*P]
    float4*       __restrict__ out)     // [B, NV]
{
    const int b = blockIdx.x;
    const int t = threadIdx.x;

    float4 a = make_float4(0.f, 0.f, 0.f, 0.f);
#pragma unroll
    for (int p = 0; p < P; ++p) {
        const float4 v = ws_sum[((size_t)(b * P + p)) * NV + t];
        a.x += v.x; a.y += v.y; a.z += v.z; a.w += v.w;
    }
    const float c = ws_cnt[b * P + 0] + ws_cnt[b * P + 1]
                  + ws_cnt[b * P + 2] + ws_cnt[b * P + 3];
    const float inv = 1.0f / c;
    out[b * NV + t] = make_float4(a.x * inv, a.y * inv, a.z * inv, a.w * inv);
}

extern "C" void kernel_launch(void* const* d_in, const int* in_sizes, int n_in,
                              void* d_out, int out_size, void* d_ws, size_t ws_size,
                              hipStream_t stream) {
    const float4* embed = (const float4*)d_in[0];
    const int* tok = (const int*)d_in[1];
    float4* out = (float4*)d_out;

    // Workspace layout: [B*P][NV] float4 partial sums, then [B*P] float counts.
    float4* ws_sum = (float4*)d_ws;
    float*  ws_cnt = (float*)((char*)d_ws + (size_t)B * P * NV * sizeof(float4));

    // npass=2: deliberate double-stream of embed for BW diagnosis.
    // Output is invariant (2*sum / 2*cnt).
    partial_kernel<<<dim3(B * P), dim3(256), 0, stream>>>(embed, tok, ws_sum, ws_cnt, 2);
    finalize_kernel<<<dim3(B), dim3(NV), 0, stream>>>(ws_sum, ws_cnt, out);
}

// Round 4
// 991.767 us; speedup vs baseline: 1.1057x; 1.1057x over previous
//
#include <hip/hip_runtime.h>

// Masked mean-pool: out[b,d] = sum_s embed[b,s,d]*mask[b,s] / sum_s mask[b,s]
// mask[b,s] = token_ids[b,s] not in {0 (PAD), 101 (CLS), 102 (SEP)}
//
// B=512, S=512, D=768, fp32. Streaming-read bound: ~805 MB embed.
// Roofline @6.3 TB/s achievable: ~128 us.
//
// V5 = revert of the V4 diagnostic (npass=2, +98us) to the best-measured
// variant (V2, 990.96 us).
//
// SESSION FINDINGS (R0-R3):
//  - V1 (192 thr, strided), V2 (768 thr, strided), V3 (2048 blocks,
//    contiguous streams, 2-kernel) all measure 991-999 us: dur_us is
//    kernel-structure-independent.
//  - V4 diagnostic: doubling the embed stream (scale-invariant output)
//    costs only +98 us -> the kernel's intrinsic pass cost is ~100-150 us,
//    i.e. at/near the 6.3 TB/s achievable-HBM roofline (128 us ideal).
//  - The remaining ~850-900 us of dur_us is fixed harness cost (the timed
//    path includes ~505 us 3.2 GB poison fills at 80% HBM peak; our kernel
//    never appears in the top-5 dispatch table). Not addressable from the
//    kernel source.

constexpr int B  = 512;
constexpr int S  = 512;
constexpr int D  = 768;
constexpr int NV = D / 4;     // 192 float4 columns
constexpr int CH = 4;         // S-chunks per block
constexpr int SCH = S / CH;   // 128 rows per chunk
constexpr int NT = NV * CH;   // 768 threads = 12 waves

__global__ __launch_bounds__(NT) void masked_mean_kernel(
    const float4* __restrict__ embed,   // [B, S, NV] as float4
    const int* __restrict__ tok,        // [B, S]
    float4* __restrict__ out)           // [B, NV]
{
    const int b = blockIdx.x;
    const int t = threadIdx.x;

    // Wave-aligned decomposition: wave w (0..11) -> chunk w/3, col base (w%3)*64.
    // Each wave's 64 lanes read 64 consecutive float4 = 1 KB coalesced.
    const int w    = t >> 6;
    const int lane = t & 63;
    const int col  = (w % 3) * 64 + lane;
    const int ch   = w / 3;

    __shared__ float  maskf[S];         // 2 KB
    __shared__ float4 accs[CH][NV];     // 12 KB
    __shared__ float  cnts[CH];

    // Stage mask for this batch row (coalesced int loads, threads 0..511).
    if (t < S) {
        const int id = tok[b * S + t];
        maskf[t] = (id != 0 && id != 101 && id != 102) ? 1.0f : 0.0f;
    }
    __syncthreads();

    // Stream this chunk's rows. maskf[s] is a same-address LDS broadcast per
    // wave, so every lane redundantly accumulates cnt -> no cross-lane reduce.
    const int s0 = ch * SCH;
    const float4* row = embed + (size_t)b * S * NV + (size_t)s0 * NV + col;
    float4 acc = make_float4(0.f, 0.f, 0.f, 0.f);
    float cnt = 0.f;

#pragma unroll 8
    for (int s = 0; s < SCH; ++s) {
        const float  m = maskf[s0 + s];
        const float4 v = row[(size_t)s * NV];
        cnt += m;
        acc.x = fmaf(v.x, m, acc.x);
        acc.y = fmaf(v.y, m, acc.y);
        acc.z = fmaf(v.z, m, acc.z);
        acc.w = fmaf(v.w, m, acc.w);
    }

    accs[ch][col] = acc;
    if (col == 0) cnts[ch] = cnt;
    __syncthreads();

    // Final reduce over chunks: threads 0..191, contiguous float4 LDS reads.
    if (t < NV) {
        float4 a = accs[0][t];
#pragma unroll
        for (int k = 1; k < CH; ++k) {
            const float4 p = accs[k][t];
            a.x += p.x; a.y += p.y; a.z += p.z; a.w += p.w;
        }
        const float c = cnts[0] + cnts[1] + cnts[2] + cnts[3];
        const float inv = 1.0f / c;
        out[b * NV + t] = make_float4(a.x * inv, a.y * inv, a.z * inv, a.w * inv);
    }
}

extern "C" void kernel_launch(void* const* d_in, const int* in_sizes, int n_in,
                              void* d_out, int out_size, void* d_ws, size_t ws_size,
                              hipStream_t stream) {
    const float4* embed = (const float4*)d_in[0];
    const int* tok = (const int*)d_in[1];
    float4* out = (float4*)d_out;

    masked_mean_kernel<<<dim3(B), dim3(NT), 0, stream>>>(embed, tok, out);
}